// Round 6
// baseline (222.369 us; speedup 1.0000x reference)
//
#include <hip/hip_runtime.h>

#define NN 8192
#define FIN 512
#define FO 64

typedef short bf16x8 __attribute__((ext_vector_type(8)));
typedef float f32x4 __attribute__((ext_vector_type(4)));

union AFrag { bf16x8 v; __bf16 b[8]; };

// ---------------- kernel 0: W[512][64] f32 -> WT[64][512] bf16 (LDS transpose)
__global__ __launch_bounds__(512) void wt_kernel(const float* __restrict__ W, __bf16* __restrict__ WT) {
    __shared__ float tile[64][65];
    const int k0 = blockIdx.x * 64;
    #pragma unroll
    for (int r = 0; r < 8; ++r) {
        const int kl = r * 8 + (threadIdx.x >> 6);
        const int f  = threadIdx.x & 63;
        tile[kl][f] = W[(size_t)(k0 + kl) * FO + f];
    }
    __syncthreads();
    const int f   = threadIdx.x >> 3;
    const int kk8 = (threadIdx.x & 7) * 8;
    unsigned u[4];
    #pragma unroll
    for (int h = 0; h < 4; ++h) {
        union { __bf16 b; unsigned short us; } lo, hi;
        lo.b = (__bf16)tile[kk8 + 2*h][f];
        hi.b = (__bf16)tile[kk8 + 2*h + 1][f];
        u[h] = (unsigned)lo.us | ((unsigned)hi.us << 16);
    }
    *(uint4*)(WT + (size_t)f * FIN + k0 + kk8) = make_uint4(u[0], u[1], u[2], u[3]);
}

// ---------------- kernel 1: Wh = x@W (bf16 MFMA), emit swizzled Wh + s + t ---
// whs layout: per 32-col block jb, per ft (0..3), per lane l: uint4 = 8 bf16
// B-fragment elems for mfma_f32_16x16x32_bf16. (verified R1-R5)
__global__ __launch_bounds__(128) void wh_kernel(
    const float* __restrict__ x, const __bf16* __restrict__ WT,
    const float* __restrict__ a, uint4* __restrict__ whs,
    float* __restrict__ s_out, float* __restrict__ t_out)
{
    __shared__ float whlds[2][16][FO + 1];
    const int w  = threadIdx.x >> 6;
    const int l  = threadIdx.x & 63;
    const int lr = l & 15, lg = l >> 4;
    const int rb = (blockIdx.x * 2 + w) * 16;

    f32x4 acc[4] = {};
    const float* xr = x + (size_t)(rb + lr) * FIN;
    const __bf16* wbase[4];
    #pragma unroll
    for (int ft = 0; ft < 4; ++ft) wbase[ft] = WT + (ft*16 + lr) * FIN;

    float4 nxa = *(const float4*)(xr + lg*4);
    float4 nxb = *(const float4*)(xr + lg*4 + 16);
    for (int ks = 0; ks < 16; ++ks) {
        const int k0 = ks*32 + lg*4;
        const float4 xa = nxa, xb = nxb;
        const int kn = (ks < 15 ? ks + 1 : 15)*32 + lg*4;
        nxa = *(const float4*)(xr + kn);
        nxb = *(const float4*)(xr + kn + 16);
        AFrag af;
        af.b[0]=(__bf16)xa.x; af.b[1]=(__bf16)xa.y; af.b[2]=(__bf16)xa.z; af.b[3]=(__bf16)xa.w;
        af.b[4]=(__bf16)xb.x; af.b[5]=(__bf16)xb.y; af.b[6]=(__bf16)xb.z; af.b[7]=(__bf16)xb.w;
        #pragma unroll
        for (int ft = 0; ft < 4; ++ft) {
            union { bf16x8 v; uint2 q[2]; } bf;
            bf.q[0] = *(const uint2*)(wbase[ft] + k0);
            bf.q[1] = *(const uint2*)(wbase[ft] + k0 + 16);
            acc[ft] = __builtin_amdgcn_mfma_f32_16x16x32_bf16(af.v, bf.v, acc[ft], 0, 0, 0);
        }
    }

    #pragma unroll
    for (int ft = 0; ft < 4; ++ft)
        #pragma unroll
        for (int q = 0; q < 4; ++q)
            whlds[w][lg*4+q][ft*16+lr] = acc[ft][q];

    float sp[4] = {0,0,0,0}, tp[4] = {0,0,0,0};
    #pragma unroll
    for (int ft = 0; ft < 4; ++ft) {
        const float a1 = a[ft*16 + lr];
        const float a2 = a[FO + ft*16 + lr];
        #pragma unroll
        for (int q = 0; q < 4; ++q) { sp[q] += acc[ft][q]*a1; tp[q] += acc[ft][q]*a2; }
    }
    #pragma unroll
    for (int d = 1; d < 16; d <<= 1) {
        #pragma unroll
        for (int q = 0; q < 4; ++q) { sp[q] += __shfl_xor(sp[q], d); tp[q] += __shfl_xor(tp[q], d); }
    }
    if (lr == 0) {
        *(float4*)(s_out + rb + lg*4) = make_float4(sp[0], sp[1], sp[2], sp[3]);
        *(float4*)(t_out + rb + lg*4) = make_float4(tp[0], tp[1], tp[2], tp[3]);
    }

    __syncthreads();

    const int jb = blockIdx.x;
    #pragma unroll
    for (int q = 0; q < 2; ++q) {
        const int ft = w*2 + q;
        const int f  = ft*16 + lr;
        unsigned u[4];
        #pragma unroll
        for (int h = 0; h < 4; ++h) {
            const int c0 = ((h & 2) ? 16 : 0) + lg*4 + (h & 1)*2;
            union { __bf16 b; unsigned short us; } lo, hi;
            lo.b = (__bf16)whlds[c0 >> 4][c0 & 15][f];
            hi.b = (__bf16)whlds[(c0+1) >> 4][(c0+1) & 15][f];
            u[h] = (unsigned)lo.us | ((unsigned)hi.us << 16);
        }
        whs[(jb*4 + ft)*64 + l] = make_uint4(u[0], u[1], u[2], u[3]);
    }
}

// ---------------- kernel 2: adj (256 MB) -> bitmask (8 MB) ----------------
// Group g = 256 cols of row g>>5 starting at (g&31)*256. Lane loads int4
// (1 KB/wave-load, pure linear stream); 4 ballots -> words m[g][k] where
// bit l of word k = adj[g>>5][(g&31)*256 + l*4 + k]. Wide loads + full
// occupancy saturate HBM even if per-wave loads serialize (R5 lesson).
__global__ __launch_bounds__(256) void mask_kernel(
    const int* __restrict__ adj, unsigned* __restrict__ mask)
{
    const int l   = threadIdx.x & 63;
    const int wid = (blockIdx.x * 256 + threadIdx.x) >> 6;   // 0..16383
    #pragma unroll 4
    for (int g = wid; g < NN * 32; g += 16384) {
        const int4 v = *(const int4*)(adj + (size_t)g * 256 + l * 4);
        const unsigned long long b0 = __ballot(v.x != 0);
        const unsigned long long b1 = __ballot(v.y != 0);
        const unsigned long long b2 = __ballot(v.z != 0);
        const unsigned long long b3 = __ballot(v.w != 0);
        if (l == 0) {
            uint4* mp = (uint4*)(mask + (size_t)g * 8);
            mp[0] = make_uint4((unsigned)b0, (unsigned)(b0 >> 32),
                               (unsigned)b1, (unsigned)(b1 >> 32));
            mp[1] = make_uint4((unsigned)b2, (unsigned)(b2 >> 32),
                               (unsigned)b3, (unsigned)(b3 >> 32));
        }
    }
}

// ---------------- kernel 3: compute-bound fused GAT ----------------
// 256 blocks x 1024 thr = 16 independent K-waves. Block owns 32 rows; wave w
// owns cols [w*512, +512): 2 groups of 256 cols x 8 iters of 32 cols.
// Mask words cached per group; bit decode: sa[k]=word_k>>lg, then
// bit(e) = (sa[e&3] >> (i2*8 + (e>=4)*4)) & 1  (compile-time shifts).
__global__ __launch_bounds__(1024, 4) void gat3_kernel(
    const unsigned* __restrict__ mask, const uint4* __restrict__ whs,
    const float* __restrict__ s_in, const float* __restrict__ t_in,
    float* __restrict__ out)
{
    __shared__ float red[8][2048];     // 64 KB reduce buffer
    __shared__ float dnl[16][32];
    __shared__ float dns[32];
    const int w  = threadIdx.x >> 6;   // 0..15
    const int l  = threadIdx.x & 63;
    const int lr = l & 15, lg = l >> 4;
    const int rg = blockIdx.x;
    const int r0 = rg * 32;
    const float sA = s_in[r0 + lr];
    const float sB = s_in[r0 + 16 + lr];
    const int sh0 = lg * 4;
    const bf16x8* wv = (const bf16x8*)whs;
    const ulonglong2* m2 = (const ulonglong2*)mask;
    const size_t gAb = ((size_t)(r0 + lr) * 32 + w*2) * 2;       // ulonglong2 idx
    const size_t gBb = ((size_t)(r0 + 16 + lr) * 32 + w*2) * 2;

    f32x4 acc[2][4] = {};
    float dnA = 0.f, dnB = 0.f;

    // 1-deep t prefetch
    float4 t0 = *(const float4*)(t_in + w*512 + sh0);
    float4 t1 = *(const float4*)(t_in + w*512 + 16 + sh0);

    #pragma unroll
    for (int h = 0; h < 2; ++h) {
        const ulonglong2 A01 = m2[gAb + h*2], A23 = m2[gAb + h*2 + 1];
        const ulonglong2 B01 = m2[gBb + h*2], B23 = m2[gBb + h*2 + 1];
        unsigned long long sa[4], sb[4];
        sa[0] = A01.x >> lg; sa[1] = A01.y >> lg; sa[2] = A23.x >> lg; sa[3] = A23.y >> lg;
        sb[0] = B01.x >> lg; sb[1] = B01.y >> lg; sb[2] = B23.x >> lg; sb[3] = B23.y >> lg;

        #pragma unroll
        for (int i2 = 0; i2 < 8; ++i2) {
            const int it = h*8 + i2;
            const int jb = w*16 + it;
            // bv for current iter: consumed after the exp chain
            bf16x8 bv0 = wv[(jb*4 + 0)*64 + l];
            bf16x8 bv1 = wv[(jb*4 + 1)*64 + l];
            bf16x8 bv2 = wv[(jb*4 + 2)*64 + l];
            bf16x8 bv3 = wv[(jb*4 + 3)*64 + l];
            // next-iter t
            const int jn = w*16 + (it + 1 < 16 ? it + 1 : 15);
            const float4 nt0 = *(const float4*)(t_in + jn*32 + sh0);
            const float4 nt1 = *(const float4*)(t_in + jn*32 + 16 + sh0);

            const float tv[8] = {t0.x, t0.y, t0.z, t0.w, t1.x, t1.y, t1.z, t1.w};
            AFrag afA, afB;
            #pragma unroll
            for (int e = 0; e < 8; ++e) {
                const int sh = i2*8 + ((e >> 2) << 2);   // compile-time
                float eA = sA + tv[e]; eA = fmaxf(eA, 0.2f * eA);
                float eB = sB + tv[e]; eB = fmaxf(eB, 0.2f * eB);
                const float pA = ((unsigned)(sa[e & 3] >> sh) & 1u) ? __expf(eA) : 0.f;
                const float pB = ((unsigned)(sb[e & 3] >> sh) & 1u) ? __expf(eB) : 0.f;
                dnA += pA; dnB += pB;
                afA.b[e] = (__bf16)pA;
                afB.b[e] = (__bf16)pB;
            }
            acc[0][0] = __builtin_amdgcn_mfma_f32_16x16x32_bf16(afA.v, bv0, acc[0][0], 0, 0, 0);
            acc[0][1] = __builtin_amdgcn_mfma_f32_16x16x32_bf16(afA.v, bv1, acc[0][1], 0, 0, 0);
            acc[0][2] = __builtin_amdgcn_mfma_f32_16x16x32_bf16(afA.v, bv2, acc[0][2], 0, 0, 0);
            acc[0][3] = __builtin_amdgcn_mfma_f32_16x16x32_bf16(afA.v, bv3, acc[0][3], 0, 0, 0);
            acc[1][0] = __builtin_amdgcn_mfma_f32_16x16x32_bf16(afB.v, bv0, acc[1][0], 0, 0, 0);
            acc[1][1] = __builtin_amdgcn_mfma_f32_16x16x32_bf16(afB.v, bv1, acc[1][1], 0, 0, 0);
            acc[1][2] = __builtin_amdgcn_mfma_f32_16x16x32_bf16(afB.v, bv2, acc[1][2], 0, 0, 0);
            acc[1][3] = __builtin_amdgcn_mfma_f32_16x16x32_bf16(afB.v, bv3, acc[1][3], 0, 0, 0);

            t0 = nt0; t1 = nt1;
        }
    }

    // per-row denominators: sum the 4 lane-groups of this wave
    dnA += __shfl_xor(dnA, 16); dnA += __shfl_xor(dnA, 32);
    dnB += __shfl_xor(dnB, 16); dnB += __shfl_xor(dnB, 32);
    if (l < 16) { dnl[w][l] = dnA; dnl[w][16 + l] = dnB; }
    __syncthreads();
    if (threadIdx.x < 32) {
        float s = 0.f;
        #pragma unroll
        for (int ww = 0; ww < 16; ++ww) s += dnl[ww][threadIdx.x];
        dns[threadIdx.x] = s;
    }

    // K-reduce acc across 16 waves (tree)
    for (int h = 8; h >= 1; h >>= 1) {
        if (w >= h && w < 2*h) {
            #pragma unroll
            for (int g = 0; g < 2; ++g)
                #pragma unroll
                for (int ft = 0; ft < 4; ++ft)
                    #pragma unroll
                    for (int q = 0; q < 4; ++q)
                        red[w - h][((g*16 + lg*4 + q)*FO) + ft*16 + lr] = acc[g][ft][q];
        }
        __syncthreads();
        if (w < h) {
            #pragma unroll
            for (int g = 0; g < 2; ++g)
                #pragma unroll
                for (int ft = 0; ft < 4; ++ft)
                    #pragma unroll
                    for (int q = 0; q < 4; ++q)
                        acc[g][ft][q] += red[w][((g*16 + lg*4 + q)*FO) + ft*16 + lr];
        }
        __syncthreads();
    }

    // epilogue: wave 0 holds 32x64. C/D map: col(feature)=lr, row m=lg*4+q
    if (w == 0) {
        #pragma unroll
        for (int g = 0; g < 2; ++g) {
            #pragma unroll
            for (int ft = 0; ft < 4; ++ft) {
                #pragma unroll
                for (int q = 0; q < 4; ++q) {
                    const int m = g*16 + lg*4 + q;
                    const float h2 = acc[g][ft][q] / dns[m];
                    out[(size_t)(r0 + m) * FO + ft*16 + lr] =
                        (h2 > 0.f) ? h2 : (__expf(h2) - 1.f);
                }
            }
        }
    }
}

extern "C" void kernel_launch(void* const* d_in, const int* in_sizes, int n_in,
                              void* d_out, int out_size, void* d_ws, size_t ws_size,
                              hipStream_t stream) {
    const float* x   = (const float*)d_in[0];
    const int*   adj = (const int*)d_in[1];
    const float* W   = (const float*)d_in[2];
    const float* a   = (const float*)d_in[3];
    float* out = (float*)d_out;

    char* ws = (char*)d_ws;
    uint4*    whs  = (uint4*)ws;                                   // 1 MiB
    __bf16*   WT   = (__bf16*)(ws + (1u << 20));                   // 64 KiB
    float*    s    = (float*)(ws + (1u << 20) + (1u << 16));       // 32 KiB
    float*    t    = (float*)(ws + (1u << 20) + (1u << 16) + 32768);
    unsigned* mask = (unsigned*)(ws + (2u << 20));                 // 8 MiB

    wt_kernel  <<<8,    512, 0, stream>>>(W, WT);
    wh_kernel  <<<256,  128, 0, stream>>>(x, WT, a, whs, s, t);
    mask_kernel<<<4096, 256, 0, stream>>>(adj, mask);
    gat3_kernel<<<256, 1024, 0, stream>>>(mask, whs, s, t, out);
}

// Round 7
// 103.921 us; speedup vs baseline: 2.1398x; 2.1398x over previous
//
#include <hip/hip_runtime.h>

#define NN 8192
#define FIN 512
#define FO 64

typedef short bf16x8 __attribute__((ext_vector_type(8)));
typedef float f32x4 __attribute__((ext_vector_type(4)));

union AFrag { bf16x8 v; __bf16 b[8]; };

// ---------------- kernel 0: W[512][64] f32 -> WT[64][512] bf16 (LDS transpose)
__global__ __launch_bounds__(512) void wt_kernel(const float* __restrict__ W, __bf16* __restrict__ WT) {
    __shared__ float tile[64][65];
    const int k0 = blockIdx.x * 64;
    #pragma unroll
    for (int r = 0; r < 8; ++r) {
        const int kl = r * 8 + (threadIdx.x >> 6);
        const int f  = threadIdx.x & 63;
        tile[kl][f] = W[(size_t)(k0 + kl) * FO + f];
    }
    __syncthreads();
    const int f   = threadIdx.x >> 3;
    const int kk8 = (threadIdx.x & 7) * 8;
    unsigned u[4];
    #pragma unroll
    for (int h = 0; h < 4; ++h) {
        union { __bf16 b; unsigned short us; } lo, hi;
        lo.b = (__bf16)tile[kk8 + 2*h][f];
        hi.b = (__bf16)tile[kk8 + 2*h + 1][f];
        u[h] = (unsigned)lo.us | ((unsigned)hi.us << 16);
    }
    *(uint4*)(WT + (size_t)f * FIN + k0 + kk8) = make_uint4(u[0], u[1], u[2], u[3]);
}

// ---------------- kernel 1: Wh = x@W (bf16 MFMA), emit swizzled Wh + s + t ---
// whs layout: per 32-col block jb, per ft (0..3), per lane l: uint4 = 8 bf16
// B-fragment elems for mfma_f32_16x16x32_bf16. (verified R1-R6)
__global__ __launch_bounds__(128) void wh_kernel(
    const float* __restrict__ x, const __bf16* __restrict__ WT,
    const float* __restrict__ a, uint4* __restrict__ whs,
    float* __restrict__ s_out, float* __restrict__ t_out)
{
    __shared__ float whlds[2][16][FO + 1];
    const int w  = threadIdx.x >> 6;
    const int l  = threadIdx.x & 63;
    const int lr = l & 15, lg = l >> 4;
    const int rb = (blockIdx.x * 2 + w) * 16;

    f32x4 acc[4] = {};
    const float* xr = x + (size_t)(rb + lr) * FIN;
    const __bf16* wbase[4];
    #pragma unroll
    for (int ft = 0; ft < 4; ++ft) wbase[ft] = WT + (ft*16 + lr) * FIN;

    float4 nxa = *(const float4*)(xr + lg*4);
    float4 nxb = *(const float4*)(xr + lg*4 + 16);
    for (int ks = 0; ks < 16; ++ks) {
        const int k0 = ks*32 + lg*4;
        const float4 xa = nxa, xb = nxb;
        const int kn = (ks < 15 ? ks + 1 : 15)*32 + lg*4;
        nxa = *(const float4*)(xr + kn);
        nxb = *(const float4*)(xr + kn + 16);
        AFrag af;
        af.b[0]=(__bf16)xa.x; af.b[1]=(__bf16)xa.y; af.b[2]=(__bf16)xa.z; af.b[3]=(__bf16)xa.w;
        af.b[4]=(__bf16)xb.x; af.b[5]=(__bf16)xb.y; af.b[6]=(__bf16)xb.z; af.b[7]=(__bf16)xb.w;
        #pragma unroll
        for (int ft = 0; ft < 4; ++ft) {
            union { bf16x8 v; uint2 q[2]; } bf;
            bf.q[0] = *(const uint2*)(wbase[ft] + k0);
            bf.q[1] = *(const uint2*)(wbase[ft] + k0 + 16);
            acc[ft] = __builtin_amdgcn_mfma_f32_16x16x32_bf16(af.v, bf.v, acc[ft], 0, 0, 0);
        }
    }

    #pragma unroll
    for (int ft = 0; ft < 4; ++ft)
        #pragma unroll
        for (int q = 0; q < 4; ++q)
            whlds[w][lg*4+q][ft*16+lr] = acc[ft][q];

    float sp[4] = {0,0,0,0}, tp[4] = {0,0,0,0};
    #pragma unroll
    for (int ft = 0; ft < 4; ++ft) {
        const float a1 = a[ft*16 + lr];
        const float a2 = a[FO + ft*16 + lr];
        #pragma unroll
        for (int q = 0; q < 4; ++q) { sp[q] += acc[ft][q]*a1; tp[q] += acc[ft][q]*a2; }
    }
    #pragma unroll
    for (int d = 1; d < 16; d <<= 1) {
        #pragma unroll
        for (int q = 0; q < 4; ++q) { sp[q] += __shfl_xor(sp[q], d); tp[q] += __shfl_xor(tp[q], d); }
    }
    if (lr == 0) {
        *(float4*)(s_out + rb + lg*4) = make_float4(sp[0], sp[1], sp[2], sp[3]);
        *(float4*)(t_out + rb + lg*4) = make_float4(tp[0], tp[1], tp[2], tp[3]);
    }

    __syncthreads();

    const int jb = blockIdx.x;
    #pragma unroll
    for (int q = 0; q < 2; ++q) {
        const int ft = w*2 + q;
        const int f  = ft*16 + lr;
        unsigned u[4];
        #pragma unroll
        for (int h = 0; h < 4; ++h) {
            const int c0 = ((h & 2) ? 16 : 0) + lg*4 + (h & 1)*2;
            union { __bf16 b; unsigned short us; } lo, hi;
            lo.b = (__bf16)whlds[c0 >> 4][c0 & 15][f];
            hi.b = (__bf16)whlds[(c0+1) >> 4][(c0+1) & 15][f];
            u[h] = (unsigned)lo.us | ((unsigned)hi.us << 16);
        }
        whs[(jb*4 + ft)*64 + l] = make_uint4(u[0], u[1], u[2], u[3]);
    }
}

// ---------------- kernel 2: adj (256 MB) -> bitmask (8 MB), R5 format -------
// mask[row*256 + jw], bit c = (adj[row][jw*32 + c] != 0).
// Wave handles a 256-col group g: 4 independent 256B coalesced NT loads
// (cols l, 64+l, 128+l, 192+l) -> 4 ballots map directly onto words
// (g&31)*8 + {0..7}. nt bit: don't allocate adj in cache (test L3 plateau).
// asm-pin forces all 4 loads in flight (R5 lesson: VGPR=4 = serial loads).
__global__ __launch_bounds__(256) void mask_kernel(
    const int* __restrict__ adj, unsigned* __restrict__ mask)
{
    const int l   = threadIdx.x & 63;
    const int wid = (blockIdx.x * 256 + threadIdx.x) >> 6;   // 0..16383
    #pragma unroll 2
    for (int g = wid; g < NN * 32; g += 16384) {
        const int* base = adj + (size_t)g * 256 + l;
        const int v0 = __builtin_nontemporal_load(base);
        const int v1 = __builtin_nontemporal_load(base + 64);
        const int v2 = __builtin_nontemporal_load(base + 128);
        const int v3 = __builtin_nontemporal_load(base + 192);
        asm volatile("" :: "v"(v0), "v"(v1), "v"(v2), "v"(v3));  // 4-deep MLP
        const unsigned long long b0 = __ballot(v0 != 0);
        const unsigned long long b1 = __ballot(v1 != 0);
        const unsigned long long b2 = __ballot(v2 != 0);
        const unsigned long long b3 = __ballot(v3 != 0);
        if (l == 0) {
            uint4* mp = (uint4*)(mask + (size_t)g * 8);
            mp[0] = make_uint4((unsigned)b0, (unsigned)(b0 >> 32),
                               (unsigned)b1, (unsigned)(b1 >> 32));
            mp[1] = make_uint4((unsigned)b2, (unsigned)(b2 >> 32),
                               (unsigned)b3, (unsigned)(b3 >> 32));
        }
    }
}

// ---------------- kernel 3: compute-bound fused GAT (R5 verbatim) ----------
// 256 blocks x 1024 thr = 16 independent K-waves. Block owns 32 rows; wave w
// owns cols [w*512, +512): 16 iters of 32 cols. Per iter: 2 mask words ->
// 16 exps/lane -> 2 A-frags (rows 0-15, 16-31) -> 8 MFMA vs shared bv.
__global__ __launch_bounds__(1024, 4) void gat3_kernel(
    const unsigned* __restrict__ mask, const uint4* __restrict__ whs,
    const float* __restrict__ s_in, const float* __restrict__ t_in,
    float* __restrict__ out)
{
    __shared__ float red[8][2048];     // 64 KB reduce buffer
    __shared__ float dnl[16][32];
    __shared__ float dns[32];
    const int w  = threadIdx.x >> 6;   // 0..15
    const int l  = threadIdx.x & 63;
    const int lr = l & 15, lg = l >> 4;
    const int rg = blockIdx.x;
    const int r0 = rg * 32;
    const float sA = s_in[r0 + lr];
    const float sB = s_in[r0 + 16 + lr];
    const unsigned* mrowA = mask + (size_t)(r0 + lr) * 256;
    const unsigned* mrowB = mask + (size_t)(r0 + 16 + lr) * 256;
    const int sh0 = lg * 4;
    const bf16x8* wv = (const bf16x8*)whs;

    f32x4 acc[2][4] = {};
    float dnA = 0.f, dnB = 0.f;

    // 1-deep prefetch of mask/t (exp chain depends on them immediately)
    unsigned mA = mrowA[w*16], mB = mrowB[w*16];
    float4 t0 = *(const float4*)(t_in + w*512 + sh0);
    float4 t1 = *(const float4*)(t_in + w*512 + 16 + sh0);

    for (int it = 0; it < 16; ++it) {
        const int jb = w*16 + it;
        // bv for current iter: consumed only after the exp chain
        bf16x8 bv0 = wv[(jb*4 + 0)*64 + l];
        bf16x8 bv1 = wv[(jb*4 + 1)*64 + l];
        bf16x8 bv2 = wv[(jb*4 + 2)*64 + l];
        bf16x8 bv3 = wv[(jb*4 + 3)*64 + l];
        // next-iter mask/t
        const int jn = w*16 + (it + 1 < 16 ? it + 1 : 15);
        const unsigned nmA = mrowA[jn], nmB = mrowB[jn];
        const float4 nt0 = *(const float4*)(t_in + jn*32 + sh0);
        const float4 nt1 = *(const float4*)(t_in + jn*32 + 16 + sh0);

        const float tv[8] = {t0.x, t0.y, t0.z, t0.w, t1.x, t1.y, t1.z, t1.w};
        AFrag afA, afB;
        #pragma unroll
        for (int e = 0; e < 8; ++e) {
            const int bit = (e < 4) ? (sh0 + e) : (12 + sh0 + e);  // 16+sh0+(e-4)
            float eA = sA + tv[e]; eA = fmaxf(eA, 0.2f * eA);
            float eB = sB + tv[e]; eB = fmaxf(eB, 0.2f * eB);
            const float pA = ((mA >> bit) & 1u) ? __expf(eA) : 0.f;
            const float pB = ((mB >> bit) & 1u) ? __expf(eB) : 0.f;
            dnA += pA; dnB += pB;
            afA.b[e] = (__bf16)pA;
            afB.b[e] = (__bf16)pB;
        }
        acc[0][0] = __builtin_amdgcn_mfma_f32_16x16x32_bf16(afA.v, bv0, acc[0][0], 0, 0, 0);
        acc[0][1] = __builtin_amdgcn_mfma_f32_16x16x32_bf16(afA.v, bv1, acc[0][1], 0, 0, 0);
        acc[0][2] = __builtin_amdgcn_mfma_f32_16x16x32_bf16(afA.v, bv2, acc[0][2], 0, 0, 0);
        acc[0][3] = __builtin_amdgcn_mfma_f32_16x16x32_bf16(afA.v, bv3, acc[0][3], 0, 0, 0);
        acc[1][0] = __builtin_amdgcn_mfma_f32_16x16x32_bf16(afB.v, bv0, acc[1][0], 0, 0, 0);
        acc[1][1] = __builtin_amdgcn_mfma_f32_16x16x32_bf16(afB.v, bv1, acc[1][1], 0, 0, 0);
        acc[1][2] = __builtin_amdgcn_mfma_f32_16x16x32_bf16(afB.v, bv2, acc[1][2], 0, 0, 0);
        acc[1][3] = __builtin_amdgcn_mfma_f32_16x16x32_bf16(afB.v, bv3, acc[1][3], 0, 0, 0);

        mA = nmA; mB = nmB; t0 = nt0; t1 = nt1;
    }

    // per-row denominators: sum the 4 lane-groups of this wave
    dnA += __shfl_xor(dnA, 16); dnA += __shfl_xor(dnA, 32);
    dnB += __shfl_xor(dnB, 16); dnB += __shfl_xor(dnB, 32);
    if (l < 16) { dnl[w][l] = dnA; dnl[w][16 + l] = dnB; }
    __syncthreads();
    if (threadIdx.x < 32) {
        float s = 0.f;
        #pragma unroll
        for (int ww = 0; ww < 16; ++ww) s += dnl[ww][threadIdx.x];
        dns[threadIdx.x] = s;
    }

    // K-reduce acc across 16 waves (tree)
    for (int h = 8; h >= 1; h >>= 1) {
        if (w >= h && w < 2*h) {
            #pragma unroll
            for (int g = 0; g < 2; ++g)
                #pragma unroll
                for (int ft = 0; ft < 4; ++ft)
                    #pragma unroll
                    for (int q = 0; q < 4; ++q)
                        red[w - h][((g*16 + lg*4 + q)*FO) + ft*16 + lr] = acc[g][ft][q];
        }
        __syncthreads();
        if (w < h) {
            #pragma unroll
            for (int g = 0; g < 2; ++g)
                #pragma unroll
                for (int ft = 0; ft < 4; ++ft)
                    #pragma unroll
                    for (int q = 0; q < 4; ++q)
                        acc[g][ft][q] += red[w][((g*16 + lg*4 + q)*FO) + ft*16 + lr];
        }
        __syncthreads();
    }

    // epilogue: wave 0 holds 32x64. C/D map: col(feature)=lr, row m=lg*4+q
    if (w == 0) {
        #pragma unroll
        for (int g = 0; g < 2; ++g) {
            #pragma unroll
            for (int ft = 0; ft < 4; ++ft) {
                #pragma unroll
                for (int q = 0; q < 4; ++q) {
                    const int m = g*16 + lg*4 + q;
                    const float h2 = acc[g][ft][q] / dns[m];
                    out[(size_t)(r0 + m) * FO + ft*16 + lr] =
                        (h2 > 0.f) ? h2 : (__expf(h2) - 1.f);
                }
            }
        }
    }
}

extern "C" void kernel_launch(void* const* d_in, const int* in_sizes, int n_in,
                              void* d_out, int out_size, void* d_ws, size_t ws_size,
                              hipStream_t stream) {
    const float* x   = (const float*)d_in[0];
    const int*   adj = (const int*)d_in[1];
    const float* W   = (const float*)d_in[2];
    const float* a   = (const float*)d_in[3];
    float* out = (float*)d_out;

    char* ws = (char*)d_ws;
    uint4*    whs  = (uint4*)ws;                                   // 1 MiB
    __bf16*   WT   = (__bf16*)(ws + (1u << 20));                   // 64 KiB
    float*    s    = (float*)(ws + (1u << 20) + (1u << 16));       // 32 KiB
    float*    t    = (float*)(ws + (1u << 20) + (1u << 16) + 32768);
    unsigned* mask = (unsigned*)(ws + (2u << 20));                 // 8 MiB

    wt_kernel  <<<8,    512, 0, stream>>>(W, WT);
    wh_kernel  <<<256,  128, 0, stream>>>(x, WT, a, whs, s, t);
    mask_kernel<<<4096, 256, 0, stream>>>(adj, mask);
    gat3_kernel<<<256, 1024, 0, stream>>>(mask, whs, s, t, out);
}

// Round 8
// 100.457 us; speedup vs baseline: 2.2136x; 1.0345x over previous
//
#include <hip/hip_runtime.h>

#define NN 8192
#define FIN 512
#define FO 64

typedef short bf16x8 __attribute__((ext_vector_type(8)));
typedef float f32x4 __attribute__((ext_vector_type(4)));

union AFrag { bf16x8 v; __bf16 b[8]; };

// bit q of an 8-bit value -> bit 4q of a 32-bit value
__device__ __forceinline__ unsigned spread8(unsigned u) {
    u = (u | (u << 12)) & 0x000F000Fu;
    u = (u | (u << 6))  & 0x03030303u;
    u = (u | (u << 3))  & 0x11111111u;
    return u;
}

// ---------------- kernel 0: W[512][64] f32 -> WT[64][512] bf16 (LDS transpose)
__global__ __launch_bounds__(512) void wt_kernel(const float* __restrict__ W, __bf16* __restrict__ WT) {
    __shared__ float tile[64][65];
    const int k0 = blockIdx.x * 64;
    #pragma unroll
    for (int r = 0; r < 8; ++r) {
        const int kl = r * 8 + (threadIdx.x >> 6);
        const int f  = threadIdx.x & 63;
        tile[kl][f] = W[(size_t)(k0 + kl) * FO + f];
    }
    __syncthreads();
    const int f   = threadIdx.x >> 3;
    const int kk8 = (threadIdx.x & 7) * 8;
    unsigned u[4];
    #pragma unroll
    for (int h = 0; h < 4; ++h) {
        union { __bf16 b; unsigned short us; } lo, hi;
        lo.b = (__bf16)tile[kk8 + 2*h][f];
        hi.b = (__bf16)tile[kk8 + 2*h + 1][f];
        u[h] = (unsigned)lo.us | ((unsigned)hi.us << 16);
    }
    *(uint4*)(WT + (size_t)f * FIN + k0 + kk8) = make_uint4(u[0], u[1], u[2], u[3]);
}

// ---------------- kernel 1: Wh = x@W (bf16 MFMA), emit swizzled Wh + s + t ---
// whs layout: per 32-col block jb, per ft (0..3), per lane l: uint4 = 8 bf16
// B-fragment elems for mfma_f32_16x16x32_bf16. (verified R1-R7)
__global__ __launch_bounds__(128) void wh_kernel(
    const float* __restrict__ x, const __bf16* __restrict__ WT,
    const float* __restrict__ a, uint4* __restrict__ whs,
    float* __restrict__ s_out, float* __restrict__ t_out)
{
    __shared__ float whlds[2][16][FO + 1];
    const int w  = threadIdx.x >> 6;
    const int l  = threadIdx.x & 63;
    const int lr = l & 15, lg = l >> 4;
    const int rb = (blockIdx.x * 2 + w) * 16;

    f32x4 acc[4] = {};
    const float* xr = x + (size_t)(rb + lr) * FIN;
    const __bf16* wbase[4];
    #pragma unroll
    for (int ft = 0; ft < 4; ++ft) wbase[ft] = WT + (ft*16 + lr) * FIN;

    float4 nxa = *(const float4*)(xr + lg*4);
    float4 nxb = *(const float4*)(xr + lg*4 + 16);
    for (int ks = 0; ks < 16; ++ks) {
        const int k0 = ks*32 + lg*4;
        const float4 xa = nxa, xb = nxb;
        const int kn = (ks < 15 ? ks + 1 : 15)*32 + lg*4;
        nxa = *(const float4*)(xr + kn);
        nxb = *(const float4*)(xr + kn + 16);
        AFrag af;
        af.b[0]=(__bf16)xa.x; af.b[1]=(__bf16)xa.y; af.b[2]=(__bf16)xa.z; af.b[3]=(__bf16)xa.w;
        af.b[4]=(__bf16)xb.x; af.b[5]=(__bf16)xb.y; af.b[6]=(__bf16)xb.z; af.b[7]=(__bf16)xb.w;
        #pragma unroll
        for (int ft = 0; ft < 4; ++ft) {
            union { bf16x8 v; uint2 q[2]; } bf;
            bf.q[0] = *(const uint2*)(wbase[ft] + k0);
            bf.q[1] = *(const uint2*)(wbase[ft] + k0 + 16);
            acc[ft] = __builtin_amdgcn_mfma_f32_16x16x32_bf16(af.v, bf.v, acc[ft], 0, 0, 0);
        }
    }

    #pragma unroll
    for (int ft = 0; ft < 4; ++ft)
        #pragma unroll
        for (int q = 0; q < 4; ++q)
            whlds[w][lg*4+q][ft*16+lr] = acc[ft][q];

    float sp[4] = {0,0,0,0}, tp[4] = {0,0,0,0};
    #pragma unroll
    for (int ft = 0; ft < 4; ++ft) {
        const float a1 = a[ft*16 + lr];
        const float a2 = a[FO + ft*16 + lr];
        #pragma unroll
        for (int q = 0; q < 4; ++q) { sp[q] += acc[ft][q]*a1; tp[q] += acc[ft][q]*a2; }
    }
    #pragma unroll
    for (int d = 1; d < 16; d <<= 1) {
        #pragma unroll
        for (int q = 0; q < 4; ++q) { sp[q] += __shfl_xor(sp[q], d); tp[q] += __shfl_xor(tp[q], d); }
    }
    if (lr == 0) {
        *(float4*)(s_out + rb + lg*4) = make_float4(sp[0], sp[1], sp[2], sp[3]);
        *(float4*)(t_out + rb + lg*4) = make_float4(tp[0], tp[1], tp[2], tp[3]);
    }

    __syncthreads();

    const int jb = blockIdx.x;
    #pragma unroll
    for (int q = 0; q < 2; ++q) {
        const int ft = w*2 + q;
        const int f  = ft*16 + lr;
        unsigned u[4];
        #pragma unroll
        for (int h = 0; h < 4; ++h) {
            const int c0 = ((h & 2) ? 16 : 0) + lg*4 + (h & 1)*2;
            union { __bf16 b; unsigned short us; } lo, hi;
            lo.b = (__bf16)whlds[c0 >> 4][c0 & 15][f];
            hi.b = (__bf16)whlds[(c0+1) >> 4][(c0+1) & 15][f];
            u[h] = (unsigned)lo.us | ((unsigned)hi.us << 16);
        }
        whs[(jb*4 + ft)*64 + l] = make_uint4(u[0], u[1], u[2], u[3]);
    }
}

// ---------------- kernel 2: adj (256 MB) -> bitmask (8 MB), R5 format -------
// mask[row*256 + jw], bit c' = (adj[row][jw*32 + c'] != 0).
// Wave handles a 256-col group per iter with ONE int4 load (1 KB/instr —
// the load-width fix: bytes-in-flight scale with instruction width).
// Lane m holds cols 4m+r (r=component) -> ballot br bit m = col 4m+r.
// Word jw needs cols jw*32+c': byte jw of each ballot, bit-spread 4x and
// interleave: word = spr(B0)|spr(B1)<<1|spr(B2)<<2|spr(B3)<<3.
__global__ __launch_bounds__(256) void mask_kernel(
    const int* __restrict__ adj, unsigned* __restrict__ mask)
{
    const int l   = threadIdx.x & 63;
    const int wid = (blockIdx.x * 256 + threadIdx.x) >> 6;   // 0..16383
    const int lsh = (l & 7) * 8;
    #pragma unroll 2
    for (int g = wid; g < NN * 32; g += 16384) {
        const int4 v = *(const int4*)(adj + (size_t)g * 256 + l * 4);
        const unsigned long long b0 = __ballot(v.x != 0);
        const unsigned long long b1 = __ballot(v.y != 0);
        const unsigned long long b2 = __ballot(v.z != 0);
        const unsigned long long b3 = __ballot(v.w != 0);
        if (l < 8) {
            const unsigned w0 = spread8((unsigned)(b0 >> lsh) & 0xFFu);
            const unsigned w1 = spread8((unsigned)(b1 >> lsh) & 0xFFu);
            const unsigned w2 = spread8((unsigned)(b2 >> lsh) & 0xFFu);
            const unsigned w3 = spread8((unsigned)(b3 >> lsh) & 0xFFu);
            mask[(size_t)g * 8 + l] = w0 | (w1 << 1) | (w2 << 2) | (w3 << 3);
        }
    }
}

// ---------------- kernel 3: compute-bound fused GAT (R5 verbatim) ----------
// 256 blocks x 1024 thr = 16 independent K-waves. Block owns 32 rows; wave w
// owns cols [w*512, +512): 16 iters of 32 cols. Per iter: 2 mask words ->
// 16 exps/lane -> 2 A-frags (rows 0-15, 16-31) -> 8 MFMA vs shared bv.
__global__ __launch_bounds__(1024, 4) void gat3_kernel(
    const unsigned* __restrict__ mask, const uint4* __restrict__ whs,
    const float* __restrict__ s_in, const float* __restrict__ t_in,
    float* __restrict__ out)
{
    __shared__ float red[8][2048];     // 64 KB reduce buffer
    __shared__ float dnl[16][32];
    __shared__ float dns[32];
    const int w  = threadIdx.x >> 6;   // 0..15
    const int l  = threadIdx.x & 63;
    const int lr = l & 15, lg = l >> 4;
    const int rg = blockIdx.x;
    const int r0 = rg * 32;
    const float sA = s_in[r0 + lr];
    const float sB = s_in[r0 + 16 + lr];
    const unsigned* mrowA = mask + (size_t)(r0 + lr) * 256;
    const unsigned* mrowB = mask + (size_t)(r0 + 16 + lr) * 256;
    const int sh0 = lg * 4;
    const bf16x8* wv = (const bf16x8*)whs;

    f32x4 acc[2][4] = {};
    float dnA = 0.f, dnB = 0.f;

    // 1-deep prefetch of mask/t (exp chain depends on them immediately)
    unsigned mA = mrowA[w*16], mB = mrowB[w*16];
    float4 t0 = *(const float4*)(t_in + w*512 + sh0);
    float4 t1 = *(const float4*)(t_in + w*512 + 16 + sh0);

    for (int it = 0; it < 16; ++it) {
        const int jb = w*16 + it;
        // bv for current iter: consumed only after the exp chain
        bf16x8 bv0 = wv[(jb*4 + 0)*64 + l];
        bf16x8 bv1 = wv[(jb*4 + 1)*64 + l];
        bf16x8 bv2 = wv[(jb*4 + 2)*64 + l];
        bf16x8 bv3 = wv[(jb*4 + 3)*64 + l];
        // next-iter mask/t
        const int jn = w*16 + (it + 1 < 16 ? it + 1 : 15);
        const unsigned nmA = mrowA[jn], nmB = mrowB[jn];
        const float4 nt0 = *(const float4*)(t_in + jn*32 + sh0);
        const float4 nt1 = *(const float4*)(t_in + jn*32 + 16 + sh0);

        const float tv[8] = {t0.x, t0.y, t0.z, t0.w, t1.x, t1.y, t1.z, t1.w};
        AFrag afA, afB;
        #pragma unroll
        for (int e = 0; e < 8; ++e) {
            const int bit = (e < 4) ? (sh0 + e) : (12 + sh0 + e);  // 16+sh0+(e-4)
            float eA = sA + tv[e]; eA = fmaxf(eA, 0.2f * eA);
            float eB = sB + tv[e]; eB = fmaxf(eB, 0.2f * eB);
            const float pA = ((mA >> bit) & 1u) ? __expf(eA) : 0.f;
            const float pB = ((mB >> bit) & 1u) ? __expf(eB) : 0.f;
            dnA += pA; dnB += pB;
            afA.b[e] = (__bf16)pA;
            afB.b[e] = (__bf16)pB;
        }
        acc[0][0] = __builtin_amdgcn_mfma_f32_16x16x32_bf16(afA.v, bv0, acc[0][0], 0, 0, 0);
        acc[0][1] = __builtin_amdgcn_mfma_f32_16x16x32_bf16(afA.v, bv1, acc[0][1], 0, 0, 0);
        acc[0][2] = __builtin_amdgcn_mfma_f32_16x16x32_bf16(afA.v, bv2, acc[0][2], 0, 0, 0);
        acc[0][3] = __builtin_amdgcn_mfma_f32_16x16x32_bf16(afA.v, bv3, acc[0][3], 0, 0, 0);
        acc[1][0] = __builtin_amdgcn_mfma_f32_16x16x32_bf16(afB.v, bv0, acc[1][0], 0, 0, 0);
        acc[1][1] = __builtin_amdgcn_mfma_f32_16x16x32_bf16(afB.v, bv1, acc[1][1], 0, 0, 0);
        acc[1][2] = __builtin_amdgcn_mfma_f32_16x16x32_bf16(afB.v, bv2, acc[1][2], 0, 0, 0);
        acc[1][3] = __builtin_amdgcn_mfma_f32_16x16x32_bf16(afB.v, bv3, acc[1][3], 0, 0, 0);

        mA = nmA; mB = nmB; t0 = nt0; t1 = nt1;
    }

    // per-row denominators: sum the 4 lane-groups of this wave
    dnA += __shfl_xor(dnA, 16); dnA += __shfl_xor(dnA, 32);
    dnB += __shfl_xor(dnB, 16); dnB += __shfl_xor(dnB, 32);
    if (l < 16) { dnl[w][l] = dnA; dnl[w][16 + l] = dnB; }
    __syncthreads();
    if (threadIdx.x < 32) {
        float s = 0.f;
        #pragma unroll
        for (int ww = 0; ww < 16; ++ww) s += dnl[ww][threadIdx.x];
        dns[threadIdx.x] = s;
    }

    // K-reduce acc across 16 waves (tree)
    for (int h = 8; h >= 1; h >>= 1) {
        if (w >= h && w < 2*h) {
            #pragma unroll
            for (int g = 0; g < 2; ++g)
                #pragma unroll
                for (int ft = 0; ft < 4; ++ft)
                    #pragma unroll
                    for (int q = 0; q < 4; ++q)
                        red[w - h][((g*16 + lg*4 + q)*FO) + ft*16 + lr] = acc[g][ft][q];
        }
        __syncthreads();
        if (w < h) {
            #pragma unroll
            for (int g = 0; g < 2; ++g)
                #pragma unroll
                for (int ft = 0; ft < 4; ++ft)
                    #pragma unroll
                    for (int q = 0; q < 4; ++q)
                        acc[g][ft][q] += red[w][((g*16 + lg*4 + q)*FO) + ft*16 + lr];
        }
        __syncthreads();
    }

    // epilogue: wave 0 holds 32x64. C/D map: col(feature)=lr, row m=lg*4+q
    if (w == 0) {
        #pragma unroll
        for (int g = 0; g < 2; ++g) {
            #pragma unroll
            for (int ft = 0; ft < 4; ++ft) {
                #pragma unroll
                for (int q = 0; q < 4; ++q) {
                    const int m = g*16 + lg*4 + q;
                    const float h2 = acc[g][ft][q] / dns[m];
                    out[(size_t)(r0 + m) * FO + ft*16 + lr] =
                        (h2 > 0.f) ? h2 : (__expf(h2) - 1.f);
                }
            }
        }
    }
}

extern "C" void kernel_launch(void* const* d_in, const int* in_sizes, int n_in,
                              void* d_out, int out_size, void* d_ws, size_t ws_size,
                              hipStream_t stream) {
    const float* x   = (const float*)d_in[0];
    const int*   adj = (const int*)d_in[1];
    const float* W   = (const float*)d_in[2];
    const float* a   = (const float*)d_in[3];
    float* out = (float*)d_out;

    char* ws = (char*)d_ws;
    uint4*    whs  = (uint4*)ws;                                   // 1 MiB
    __bf16*   WT   = (__bf16*)(ws + (1u << 20));                   // 64 KiB
    float*    s    = (float*)(ws + (1u << 20) + (1u << 16));       // 32 KiB
    float*    t    = (float*)(ws + (1u << 20) + (1u << 16) + 32768);
    unsigned* mask = (unsigned*)(ws + (2u << 20));                 // 8 MiB

    wt_kernel  <<<8,    512, 0, stream>>>(W, WT);
    wh_kernel  <<<256,  128, 0, stream>>>(x, WT, a, whs, s, t);
    mask_kernel<<<4096, 256, 0, stream>>>(adj, mask);
    gat3_kernel<<<256, 1024, 0, stream>>>(mask, whs, s, t, out);
}

// Round 9
// 89.772 us; speedup vs baseline: 2.4770x; 1.1190x over previous
//
#include <hip/hip_runtime.h>

#define NN 8192
#define FIN 512
#define FO 64

typedef short bf16x8 __attribute__((ext_vector_type(8)));
typedef float f32x4 __attribute__((ext_vector_type(4)));

union AFrag { bf16x8 v; __bf16 b[8]; };

// bit q of an 8-bit value -> bit 4q of a 32-bit value
__device__ __forceinline__ unsigned spread8(unsigned u) {
    u = (u | (u << 12)) & 0x000F000Fu;
    u = (u | (u << 6))  & 0x03030303u;
    u = (u | (u << 3))  & 0x11111111u;
    return u;
}

// ---------------- kernel 1: FAT = wh-role (blocks 0..127) + mask-role -------
// wh-role: Wh = x@W via MFMA, B-fragments gathered straight from W (f32,
// L1/L2-hot 64B segments) -- no WT pre-transpose kernel needed. Emits
// swizzled whs + s + t (layouts identical to R1-R8, verified).
// mask-role: adj (256 MB) -> bitmask (8 MB), R8 int4-stream code verbatim.
// wh blocks are FIRST in dispatch order so they hide inside the ~84us
// adj-stream shadow (read-link-bound; mask barely uses CU resources).
__global__ __launch_bounds__(256, 5) void fat_kernel(
    const int* __restrict__ adj, unsigned* __restrict__ mask,
    const float* __restrict__ x, const float* __restrict__ W,
    const float* __restrict__ a, uint4* __restrict__ whs,
    float* __restrict__ s_out, float* __restrict__ t_out)
{
    __shared__ float whlds[4][16][FO + 1];
    const int l  = threadIdx.x & 63;

    if (blockIdx.x >= 128) {
        // ------------------ mask role (R8 verbatim, unroll 4) ------------------
        const int mb  = blockIdx.x - 128;
        const int wid = (mb * 256 + (int)threadIdx.x) >> 6;   // 0..16383
        const int lsh = (l & 7) * 8;
        #pragma unroll 4
        for (int g = wid; g < NN * 32; g += 16384) {
            const int4 v = *(const int4*)(adj + (size_t)g * 256 + l * 4);
            const unsigned long long b0 = __ballot(v.x != 0);
            const unsigned long long b1 = __ballot(v.y != 0);
            const unsigned long long b2 = __ballot(v.z != 0);
            const unsigned long long b3 = __ballot(v.w != 0);
            if (l < 8) {
                const unsigned w0 = spread8((unsigned)(b0 >> lsh) & 0xFFu);
                const unsigned w1 = spread8((unsigned)(b1 >> lsh) & 0xFFu);
                const unsigned w2 = spread8((unsigned)(b2 >> lsh) & 0xFFu);
                const unsigned w3 = spread8((unsigned)(b3 >> lsh) & 0xFFu);
                mask[(size_t)g * 8 + l] = w0 | (w1 << 1) | (w2 << 2) | (w3 << 3);
            }
        }
        return;
    }

    // ------------------ wh role: 4 waves x 16 rows = 64 rows/block ----------
    const int w  = threadIdx.x >> 6;    // 0..3
    const int lr = l & 15, lg = l >> 4;
    const int rb = (blockIdx.x * 4 + w) * 16;

    f32x4 acc[4] = {};
    const float* xr = x + (size_t)(rb + lr) * FIN;

    float4 nxa = *(const float4*)(xr + lg*4);
    float4 nxb = *(const float4*)(xr + lg*4 + 16);
    for (int ks = 0; ks < 16; ++ks) {
        const int k0 = ks*32 + lg*4;
        const float4 xa = nxa, xb = nxb;
        const int kn = (ks < 15 ? ks + 1 : 15)*32 + lg*4;
        nxa = *(const float4*)(xr + kn);
        nxb = *(const float4*)(xr + kn + 16);
        AFrag af;
        af.b[0]=(__bf16)xa.x; af.b[1]=(__bf16)xa.y; af.b[2]=(__bf16)xa.z; af.b[3]=(__bf16)xa.w;
        af.b[4]=(__bf16)xb.x; af.b[5]=(__bf16)xb.y; af.b[6]=(__bf16)xb.z; af.b[7]=(__bf16)xb.w;
        #pragma unroll
        for (int ft = 0; ft < 4; ++ft) {
            const int f = ft*16 + lr;
            AFrag bf;
            #pragma unroll
            for (int j = 0; j < 4; ++j) {
                bf.b[j]     = (__bf16)W[(size_t)(k0 + j) * FO + f];
                bf.b[4 + j] = (__bf16)W[(size_t)(k0 + 16 + j) * FO + f];
            }
            acc[ft] = __builtin_amdgcn_mfma_f32_16x16x32_bf16(af.v, bf.v, acc[ft], 0, 0, 0);
        }
    }

    #pragma unroll
    for (int ft = 0; ft < 4; ++ft)
        #pragma unroll
        for (int q = 0; q < 4; ++q)
            whlds[w][lg*4+q][ft*16+lr] = acc[ft][q];

    float sp[4] = {0,0,0,0}, tp[4] = {0,0,0,0};
    #pragma unroll
    for (int ft = 0; ft < 4; ++ft) {
        const float a1 = a[ft*16 + lr];
        const float a2 = a[FO + ft*16 + lr];
        #pragma unroll
        for (int q = 0; q < 4; ++q) { sp[q] += acc[ft][q]*a1; tp[q] += acc[ft][q]*a2; }
    }
    #pragma unroll
    for (int d = 1; d < 16; d <<= 1) {
        #pragma unroll
        for (int q = 0; q < 4; ++q) { sp[q] += __shfl_xor(sp[q], d); tp[q] += __shfl_xor(tp[q], d); }
    }
    if (lr == 0) {
        *(float4*)(s_out + rb + lg*4) = make_float4(sp[0], sp[1], sp[2], sp[3]);
        *(float4*)(t_out + rb + lg*4) = make_float4(tp[0], tp[1], tp[2], tp[3]);
    }

    __syncthreads();

    // swizzled fragment store: block's 64 rows = col-blocks bid*2 + half.
    // Half h lives in whlds[h*2 + 0/1]; waves (h*2, h*2+1) wrote rows
    // [bid*64 + h*32, +16) and +16..+32. wp = w&1 plays the old 2-wave role.
    const int half = w >> 1;
    const int wp   = w & 1;
    const int jb   = blockIdx.x * 2 + half;
    #pragma unroll
    for (int q = 0; q < 2; ++q) {
        const int ft = wp*2 + q;
        const int f  = ft*16 + lr;
        unsigned u[4];
        #pragma unroll
        for (int h = 0; h < 4; ++h) {
            const int c0 = ((h & 2) ? 16 : 0) + lg*4 + (h & 1)*2;
            union { __bf16 b; unsigned short us; } lo, hi;
            lo.b = (__bf16)whlds[half*2 + (c0 >> 4)][c0 & 15][f];
            hi.b = (__bf16)whlds[half*2 + ((c0+1) >> 4)][(c0+1) & 15][f];
            u[h] = (unsigned)lo.us | ((unsigned)hi.us << 16);
        }
        whs[(jb*4 + ft)*64 + l] = make_uint4(u[0], u[1], u[2], u[3]);
    }
}

// ---------------- kernel 2: compute-bound fused GAT (R5 verbatim) ----------
// 256 blocks x 1024 thr = 16 independent K-waves. Block owns 32 rows; wave w
// owns cols [w*512, +512): 16 iters of 32 cols. Per iter: 2 mask words ->
// 16 exps/lane -> 2 A-frags (rows 0-15, 16-31) -> 8 MFMA vs shared bv.
__global__ __launch_bounds__(1024, 4) void gat3_kernel(
    const unsigned* __restrict__ mask, const uint4* __restrict__ whs,
    const float* __restrict__ s_in, const float* __restrict__ t_in,
    float* __restrict__ out)
{
    __shared__ float red[8][2048];     // 64 KB reduce buffer
    __shared__ float dnl[16][32];
    __shared__ float dns[32];
    const int w  = threadIdx.x >> 6;   // 0..15
    const int l  = threadIdx.x & 63;
    const int lr = l & 15, lg = l >> 4;
    const int rg = blockIdx.x;
    const int r0 = rg * 32;
    const float sA = s_in[r0 + lr];
    const float sB = s_in[r0 + 16 + lr];
    const unsigned* mrowA = mask + (size_t)(r0 + lr) * 256;
    const unsigned* mrowB = mask + (size_t)(r0 + 16 + lr) * 256;
    const int sh0 = lg * 4;
    const bf16x8* wv = (const bf16x8*)whs;

    f32x4 acc[2][4] = {};
    float dnA = 0.f, dnB = 0.f;

    // 1-deep prefetch of mask/t (exp chain depends on them immediately)
    unsigned mA = mrowA[w*16], mB = mrowB[w*16];
    float4 t0 = *(const float4*)(t_in + w*512 + sh0);
    float4 t1 = *(const float4*)(t_in + w*512 + 16 + sh0);

    for (int it = 0; it < 16; ++it) {
        const int jb = w*16 + it;
        // bv for current iter: consumed only after the exp chain
        bf16x8 bv0 = wv[(jb*4 + 0)*64 + l];
        bf16x8 bv1 = wv[(jb*4 + 1)*64 + l];
        bf16x8 bv2 = wv[(jb*4 + 2)*64 + l];
        bf16x8 bv3 = wv[(jb*4 + 3)*64 + l];
        // next-iter mask/t
        const int jn = w*16 + (it + 1 < 16 ? it + 1 : 15);
        const unsigned nmA = mrowA[jn], nmB = mrowB[jn];
        const float4 nt0 = *(const float4*)(t_in + jn*32 + sh0);
        const float4 nt1 = *(const float4*)(t_in + jn*32 + 16 + sh0);

        const float tv[8] = {t0.x, t0.y, t0.z, t0.w, t1.x, t1.y, t1.z, t1.w};
        AFrag afA, afB;
        #pragma unroll
        for (int e = 0; e < 8; ++e) {
            const int bit = (e < 4) ? (sh0 + e) : (12 + sh0 + e);  // 16+sh0+(e-4)
            float eA = sA + tv[e]; eA = fmaxf(eA, 0.2f * eA);
            float eB = sB + tv[e]; eB = fmaxf(eB, 0.2f * eB);
            const float pA = ((mA >> bit) & 1u) ? __expf(eA) : 0.f;
            const float pB = ((mB >> bit) & 1u) ? __expf(eB) : 0.f;
            dnA += pA; dnB += pB;
            afA.b[e] = (__bf16)pA;
            afB.b[e] = (__bf16)pB;
        }
        acc[0][0] = __builtin_amdgcn_mfma_f32_16x16x32_bf16(afA.v, bv0, acc[0][0], 0, 0, 0);
        acc[0][1] = __builtin_amdgcn_mfma_f32_16x16x32_bf16(afA.v, bv1, acc[0][1], 0, 0, 0);
        acc[0][2] = __builtin_amdgcn_mfma_f32_16x16x32_bf16(afA.v, bv2, acc[0][2], 0, 0, 0);
        acc[0][3] = __builtin_amdgcn_mfma_f32_16x16x32_bf16(afA.v, bv3, acc[0][3], 0, 0, 0);
        acc[1][0] = __builtin_amdgcn_mfma_f32_16x16x32_bf16(afB.v, bv0, acc[1][0], 0, 0, 0);
        acc[1][1] = __builtin_amdgcn_mfma_f32_16x16x32_bf16(afB.v, bv1, acc[1][1], 0, 0, 0);
        acc[1][2] = __builtin_amdgcn_mfma_f32_16x16x32_bf16(afB.v, bv2, acc[1][2], 0, 0, 0);
        acc[1][3] = __builtin_amdgcn_mfma_f32_16x16x32_bf16(afB.v, bv3, acc[1][3], 0, 0, 0);

        mA = nmA; mB = nmB; t0 = nt0; t1 = nt1;
    }

    // per-row denominators: sum the 4 lane-groups of this wave
    dnA += __shfl_xor(dnA, 16); dnA += __shfl_xor(dnA, 32);
    dnB += __shfl_xor(dnB, 16); dnB += __shfl_xor(dnB, 32);
    if (l < 16) { dnl[w][l] = dnA; dnl[w][16 + l] = dnB; }
    __syncthreads();
    if (threadIdx.x < 32) {
        float s = 0.f;
        #pragma unroll
        for (int ww = 0; ww < 16; ++ww) s += dnl[ww][threadIdx.x];
        dns[threadIdx.x] = s;
    }

    // K-reduce acc across 16 waves (tree)
    for (int h = 8; h >= 1; h >>= 1) {
        if (w >= h && w < 2*h) {
            #pragma unroll
            for (int g = 0; g < 2; ++g)
                #pragma unroll
                for (int ft = 0; ft < 4; ++ft)
                    #pragma unroll
                    for (int q = 0; q < 4; ++q)
                        red[w - h][((g*16 + lg*4 + q)*FO) + ft*16 + lr] = acc[g][ft][q];
        }
        __syncthreads();
        if (w < h) {
            #pragma unroll
            for (int g = 0; g < 2; ++g)
                #pragma unroll
                for (int ft = 0; ft < 4; ++ft)
                    #pragma unroll
                    for (int q = 0; q < 4; ++q)
                        acc[g][ft][q] += red[w][((g*16 + lg*4 + q)*FO) + ft*16 + lr];
        }
        __syncthreads();
    }

    // epilogue: wave 0 holds 32x64. C/D map: col(feature)=lr, row m=lg*4+q
    if (w == 0) {
        #pragma unroll
        for (int g = 0; g < 2; ++g) {
            #pragma unroll
            for (int ft = 0; ft < 4; ++ft) {
                #pragma unroll
                for (int q = 0; q < 4; ++q) {
                    const int m = g*16 + lg*4 + q;
                    const float h2 = acc[g][ft][q] / dns[m];
                    out[(size_t)(r0 + m) * FO + ft*16 + lr] =
                        (h2 > 0.f) ? h2 : (__expf(h2) - 1.f);
                }
            }
        }
    }
}

extern "C" void kernel_launch(void* const* d_in, const int* in_sizes, int n_in,
                              void* d_out, int out_size, void* d_ws, size_t ws_size,
                              hipStream_t stream) {
    const float* x   = (const float*)d_in[0];
    const int*   adj = (const int*)d_in[1];
    const float* W   = (const float*)d_in[2];
    const float* a   = (const float*)d_in[3];
    float* out = (float*)d_out;

    char* ws = (char*)d_ws;
    uint4*    whs  = (uint4*)ws;                                   // 1 MiB
    float*    s    = (float*)(ws + (1u << 20) + (1u << 16));       // 32 KiB
    float*    t    = (float*)(ws + (1u << 20) + (1u << 16) + 32768);
    unsigned* mask = (unsigned*)(ws + (2u << 20));                 // 8 MiB

    fat_kernel <<<4224, 256, 0, stream>>>(adj, mask, x, W, a, whs, s, t);
    gat3_kernel<<<256, 1024, 0, stream>>>(mask, whs, s, t, out);
}